// Round 1
// baseline (128.950 us; speedup 1.0000x reference)
//
#include <hip/hip_runtime.h>
#include <hip/hip_bf16.h>
#include <stdint.h>

// Problem: B=16, S=1024, IN=1024, OUT=1024.
// Reference collapses: softmax row-sums are exactly 1 (key mask always has >=1
// live column), so out = leaky_relu(xs @ (Wlin@Wv)^T + (Wlin@bv + blin)).

#define M_TOT 16384   // B*S
#define KDIM  1024
#define NDIM  1024

typedef __attribute__((ext_vector_type(8))) short bf16x8;
typedef __attribute__((ext_vector_type(4))) float f32x4;
typedef __attribute__((ext_vector_type(4))) unsigned short u16x4;

static __device__ __forceinline__ unsigned short f2bf(float f) {
    union { float f; unsigned int u; } v; v.f = f;
    unsigned int u = v.u;
    return (unsigned short)((u + 0x7fffu + ((u >> 16) & 1u)) >> 16);  // RNE
}

static __device__ __forceinline__ void gload16(const void* g, void* l) {
    __builtin_amdgcn_global_load_lds(
        (__attribute__((address_space(1))) void*)(g),
        (__attribute__((address_space(3))) void*)(l), 16, 0, 0);
}

// ---------------- bcomb[o] = sum_d Wlin[o][d]*bv[d] + blin[o] ----------------
__global__ __launch_bounds__(256) void bias_kernel(
    const float* __restrict__ Wlin, const float* __restrict__ bv,
    const float* __restrict__ blin, float* __restrict__ bcomb) {
    const int wave = threadIdx.x >> 6, lane = threadIdx.x & 63;
    const int o = blockIdx.x * 4 + wave;
    float s = 0.f;
    for (int d = lane; d < KDIM; d += 64) s += Wlin[o * KDIM + d] * bv[d];
    #pragma unroll
    for (int off = 32; off > 0; off >>= 1) s += __shfl_down(s, off, 64);
    if (lane == 0) bcomb[o] = s + blin[o];
}

// ------------- Wc[o][i] = sum_d Wlin[o][d]*Wv[d][i]  (bf16 out) --------------
// 64x64 tiles, BK=32, 4 waves (2x2 of 32x32), grid 16x16=256 blocks.
__global__ __launch_bounds__(256) void wcomb_kernel(
    const float* __restrict__ Wlin, const float* __restrict__ Wv,
    unsigned short* __restrict__ Wc) {
    __shared__ unsigned short Al[64 * 32];
    __shared__ unsigned short Bl[64 * 32];
    const int t = threadIdx.x;
    const int ot = blockIdx.x >> 4;
    const int it = blockIdx.x & 15;
    const int w = t >> 6, l = t & 63;
    const int wr = (w >> 1) * 32, wc = (w & 1) * 32;
    const int lr = l & 15, lk = l >> 4;

    f32x4 acc[2][2] = {};

    for (int kt = 0; kt < KDIM / 32; ++kt) {
        // A: 64x32 fp32, 2 x float4 per thread
        float4 av[2];
        #pragma unroll
        for (int j = 0; j < 2; ++j) {
            const int row = j * 32 + (t >> 3);
            const int kq = t & 7;
            av[j] = *(const float4*)&Wlin[(ot * 64 + row) * KDIM + kt * 32 + kq * 4];
        }
        // B: Wv[d][i] 32x64 fp32, transpose into Bl[i][d]; 2 x float4 per thread
        float4 bvv[2];
        #pragma unroll
        for (int j = 0; j < 2; ++j) {
            const int d = j * 16 + (t >> 4);
            const int i4 = t & 15;
            bvv[j] = *(const float4*)&Wv[(kt * 32 + d) * NDIM + it * 64 + i4 * 4];
        }
        __syncthreads();
        #pragma unroll
        for (int j = 0; j < 2; ++j) {
            const int row = j * 32 + (t >> 3);
            const int kq = t & 7;
            u16x4 p = { f2bf(av[j].x), f2bf(av[j].y), f2bf(av[j].z), f2bf(av[j].w) };
            *(u16x4*)&Al[row * 32 + kq * 4] = p;
        }
        #pragma unroll
        for (int j = 0; j < 2; ++j) {
            const int d = j * 16 + (t >> 4);
            const int i4 = t & 15;
            Bl[(i4 * 4 + 0) * 32 + d] = f2bf(bvv[j].x);
            Bl[(i4 * 4 + 1) * 32 + d] = f2bf(bvv[j].y);
            Bl[(i4 * 4 + 2) * 32 + d] = f2bf(bvv[j].z);
            Bl[(i4 * 4 + 3) * 32 + d] = f2bf(bvv[j].w);
        }
        __syncthreads();
        bf16x8 af[2], bfr[2];
        #pragma unroll
        for (int fi = 0; fi < 2; ++fi)
            af[fi] = *(bf16x8*)&Al[(wr + fi * 16 + lr) * 32 + lk * 8];
        #pragma unroll
        for (int fj = 0; fj < 2; ++fj)
            bfr[fj] = *(bf16x8*)&Bl[(wc + fj * 16 + lr) * 32 + lk * 8];
        #pragma unroll
        for (int fi = 0; fi < 2; ++fi)
            #pragma unroll
            for (int fj = 0; fj < 2; ++fj)
                acc[fi][fj] = __builtin_amdgcn_mfma_f32_16x16x32_bf16(
                    af[fi], bfr[fj], acc[fi][fj], 0, 0, 0);
        __syncthreads();
    }
    #pragma unroll
    for (int fi = 0; fi < 2; ++fi)
        #pragma unroll
        for (int fj = 0; fj < 2; ++fj)
            #pragma unroll
            for (int r = 0; r < 4; ++r) {
                const int o = ot * 64 + wr + fi * 16 + lk * 4 + r;
                const int i = it * 64 + wc + fj * 16 + lr;
                Wc[o * KDIM + i] = f2bf(acc[fi][fj][r]);
            }
}

// ---------- out[m][n] = leaky( sum_k X[m][k]*Wc[n][k] + bcomb[n] ) -----------
// 128x128 tile, BK=32, 4 waves (2x2 of 64x64), A reg-staged fp32->bf16,
// B via global_load_lds width-16. Grid = 128*8 = 1024 blocks.
__global__ __launch_bounds__(256) void main_gemm(
    const float* __restrict__ X, const unsigned short* __restrict__ Wc,
    const float* __restrict__ bcomb, float* __restrict__ out) {
    __shared__ unsigned short As[128 * 32];
    __shared__ unsigned short Bs[128 * 32];
    const int t = threadIdx.x;
    const int nt = blockIdx.x & 7;
    const int mt = blockIdx.x >> 3;
    const int w = t >> 6, l = t & 63;
    const int wr = (w >> 1) * 64, wc = (w & 1) * 64;
    const int lr = l & 15, lk = l >> 4;

    f32x4 acc[4][4] = {};

    const int arow = t >> 3;   // + j*32
    const int akq = t & 7;
    const int brow = t >> 2;   // + j*64
    const int bc4 = t & 3;

    for (int kt = 0; kt < KDIM / 32; ++kt) {
        // A: 128x32 fp32 = 4 x float4 per thread (issue loads early)
        float4 av[4];
        #pragma unroll
        for (int j = 0; j < 4; ++j) {
            const int row = j * 32 + arow;
            av[j] = *(const float4*)&X[(mt * 128 + row) * KDIM + kt * 32 + akq * 4];
        }
        __syncthreads();  // prev iter's ds_reads done before overwrite
        #pragma unroll
        for (int j = 0; j < 4; ++j) {
            const int row = j * 32 + arow;
            u16x4 p = { f2bf(av[j].x), f2bf(av[j].y), f2bf(av[j].z), f2bf(av[j].w) };
            *(u16x4*)&As[row * 32 + akq * 4] = p;
        }
        // B: 128x32 bf16 = 8KB, 2 x 16B per thread via global_load_lds
        #pragma unroll
        for (int j = 0; j < 2; ++j) {
            const int row = j * 64 + brow;
            const unsigned short* g = &Wc[(nt * 128 + row) * KDIM + kt * 32 + bc4 * 8];
            unsigned short* ldst = &Bs[(j * 256 + w * 64) * 8];  // wave-uniform base
            gload16(g, ldst);
        }
        __syncthreads();  // barrier drains lgkm + vmcnt
        bf16x8 af[4], bfr[4];
        #pragma unroll
        for (int fi = 0; fi < 4; ++fi)
            af[fi] = *(bf16x8*)&As[(wr + fi * 16 + lr) * 32 + lk * 8];
        #pragma unroll
        for (int fj = 0; fj < 4; ++fj)
            bfr[fj] = *(bf16x8*)&Bs[(wc + fj * 16 + lr) * 32 + lk * 8];
        #pragma unroll
        for (int fi = 0; fi < 4; ++fi)
            #pragma unroll
            for (int fj = 0; fj < 4; ++fj)
                acc[fi][fj] = __builtin_amdgcn_mfma_f32_16x16x32_bf16(
                    af[fi], bfr[fj], acc[fi][fj], 0, 0, 0);
    }

    // epilogue: + bias, leaky_relu, fp32 store
    #pragma unroll
    for (int fi = 0; fi < 4; ++fi)
        #pragma unroll
        for (int fj = 0; fj < 4; ++fj) {
            const int col = nt * 128 + wc + fj * 16 + lr;
            const float b = bcomb[col];
            #pragma unroll
            for (int r = 0; r < 4; ++r) {
                const int row = mt * 128 + wr + fi * 16 + lk * 4 + r;
                float v = acc[fi][fj][r] + b;
                out[row * NDIM + col] = v >= 0.f ? v : 0.01f * v;
            }
        }
}

extern "C" void kernel_launch(void* const* d_in, const int* in_sizes, int n_in,
                              void* d_out, int out_size, void* d_ws, size_t ws_size,
                              hipStream_t stream) {
    const float* xs   = (const float*)d_in[0];
    // d_in[1] mask unused: softmax row-sums are exactly 1.
    const float* Wv   = (const float*)d_in[6];
    const float* bv   = (const float*)d_in[7];
    const float* Wlin = (const float*)d_in[8];
    const float* blin = (const float*)d_in[9];

    unsigned short* Wc = (unsigned short*)d_ws;                      // 2 MB bf16
    float* bcomb = (float*)((char*)d_ws + (size_t)NDIM * KDIM * 2);  // 4 KB fp32
    float* out = (float*)d_out;

    hipLaunchKernelGGL(bias_kernel, dim3(NDIM / 4), dim3(256), 0, stream,
                       Wlin, bv, blin, bcomb);
    hipLaunchKernelGGL(wcomb_kernel, dim3(256), dim3(256), 0, stream,
                       Wlin, Wv, Wc);
    hipLaunchKernelGGL(main_gemm, dim3((M_TOT / 128) * (NDIM / 128)), dim3(256),
                       0, stream, xs, Wc, bcomb, out);
}

// Round 2
// 104.198 us; speedup vs baseline: 1.2375x; 1.2375x over previous
//
#include <hip/hip_runtime.h>
#include <hip/hip_bf16.h>
#include <stdint.h>

// Problem: B=16, S=1024, IN=1024, OUT=1024.
// Reference collapses: softmax row-sums are exactly 1 (key mask always has >=1
// live column), so out = leaky_relu(xs @ (Wlin@Wv)^T + (Wlin@bv + blin)).
//
// Round 2: pre-convert xs -> bf16 once (was fused & 8x-redundant in the GEMM
// K-loop, making it VALU-bound at MfmaUtil=13%). Main GEMM is now pure-bf16
// m97-structure: both operands via global_load_lds width-16.

#define M_TOT 16384   // B*S
#define KDIM  1024
#define NDIM  1024

typedef __attribute__((ext_vector_type(8))) short bf16x8;
typedef __attribute__((ext_vector_type(4))) float f32x4;
typedef __attribute__((ext_vector_type(4))) unsigned short u16x4;
typedef __attribute__((ext_vector_type(8))) unsigned short u16x8;

static __device__ __forceinline__ unsigned short f2bf(float f) {
    union { float f; unsigned int u; } v; v.f = f;
    unsigned int u = v.u;
    return (unsigned short)((u + 0x7fffu + ((u >> 16) & 1u)) >> 16);  // RNE
}

static __device__ __forceinline__ void gload16(const void* g, void* l) {
    __builtin_amdgcn_global_load_lds(
        (__attribute__((address_space(1))) void*)(g),
        (__attribute__((address_space(3))) void*)(l), 16, 0, 0);
}

// ---------------------------------------------------------------------------
// prep_kernel: one dispatch, three roles by blockIdx:
//   [0,256)    : Wc[o][i] = sum_d Wlin[o][d]*Wv[d][i]  (bf16 out, 64x64 tiles)
//   [256,512)  : bcomb[o] = Wlin[o]·bv + blin[o]
//   [512,2560) : Xb = bf16(xs)   (16M elems, 8/thread x 4 iters)
// ---------------------------------------------------------------------------
__global__ __launch_bounds__(256) void prep_kernel(
    const float* __restrict__ xs, const float* __restrict__ Wv,
    const float* __restrict__ bv, const float* __restrict__ Wlin,
    const float* __restrict__ blin, unsigned short* __restrict__ Wc,
    float* __restrict__ bcomb, unsigned short* __restrict__ Xb) {
    __shared__ unsigned short Al[64 * 32];
    __shared__ unsigned short Bl[64 * 32];
    const int bid = blockIdx.x;
    const int t = threadIdx.x;

    if (bid < 256) {
        // ---- Wcomb 64x64 tile, BK=32, 4 waves (2x2 of 32x32) ----
        const int ot = bid >> 4;
        const int it = bid & 15;
        const int w = t >> 6, l = t & 63;
        const int wr = (w >> 1) * 32, wc = (w & 1) * 32;
        const int lr = l & 15, lk = l >> 4;

        f32x4 acc[2][2] = {};

        for (int kt = 0; kt < KDIM / 32; ++kt) {
            float4 av[2];
            #pragma unroll
            for (int j = 0; j < 2; ++j) {
                const int row = j * 32 + (t >> 3);
                const int kq = t & 7;
                av[j] = *(const float4*)&Wlin[(ot * 64 + row) * KDIM + kt * 32 + kq * 4];
            }
            float4 bvv[2];
            #pragma unroll
            for (int j = 0; j < 2; ++j) {
                const int d = j * 16 + (t >> 4);
                const int i4 = t & 15;
                bvv[j] = *(const float4*)&Wv[(kt * 32 + d) * NDIM + it * 64 + i4 * 4];
            }
            __syncthreads();
            #pragma unroll
            for (int j = 0; j < 2; ++j) {
                const int row = j * 32 + (t >> 3);
                const int kq = t & 7;
                u16x4 p = { f2bf(av[j].x), f2bf(av[j].y), f2bf(av[j].z), f2bf(av[j].w) };
                *(u16x4*)&Al[row * 32 + kq * 4] = p;
            }
            #pragma unroll
            for (int j = 0; j < 2; ++j) {
                const int d = j * 16 + (t >> 4);
                const int i4 = t & 15;
                Bl[(i4 * 4 + 0) * 32 + d] = f2bf(bvv[j].x);
                Bl[(i4 * 4 + 1) * 32 + d] = f2bf(bvv[j].y);
                Bl[(i4 * 4 + 2) * 32 + d] = f2bf(bvv[j].z);
                Bl[(i4 * 4 + 3) * 32 + d] = f2bf(bvv[j].w);
            }
            __syncthreads();
            bf16x8 af[2], bfr[2];
            #pragma unroll
            for (int fi = 0; fi < 2; ++fi)
                af[fi] = *(bf16x8*)&Al[(wr + fi * 16 + lr) * 32 + lk * 8];
            #pragma unroll
            for (int fj = 0; fj < 2; ++fj)
                bfr[fj] = *(bf16x8*)&Bl[(wc + fj * 16 + lr) * 32 + lk * 8];
            #pragma unroll
            for (int fi = 0; fi < 2; ++fi)
                #pragma unroll
                for (int fj = 0; fj < 2; ++fj)
                    acc[fi][fj] = __builtin_amdgcn_mfma_f32_16x16x32_bf16(
                        af[fi], bfr[fj], acc[fi][fj], 0, 0, 0);
            __syncthreads();
        }
        #pragma unroll
        for (int fi = 0; fi < 2; ++fi)
            #pragma unroll
            for (int fj = 0; fj < 2; ++fj)
                #pragma unroll
                for (int r = 0; r < 4; ++r) {
                    const int o = ot * 64 + wr + fi * 16 + lk * 4 + r;
                    const int i = it * 64 + wc + fj * 16 + lr;
                    Wc[o * KDIM + i] = f2bf(acc[fi][fj][r]);
                }
    } else if (bid < 512) {
        // ---- bias fold ----
        const int wave = t >> 6, lane = t & 63;
        const int o = (bid - 256) * 4 + wave;
        float s = 0.f;
        for (int d = lane; d < KDIM; d += 64) s += Wlin[o * KDIM + d] * bv[d];
        #pragma unroll
        for (int off = 32; off > 0; off >>= 1) s += __shfl_down(s, off, 64);
        if (lane == 0) bcomb[o] = s + blin[o];
    } else {
        // ---- xs -> bf16 ----
        const int cb = bid - 512;
        const size_t base = ((size_t)cb * 256 + t) * 8;
        #pragma unroll
        for (int itr = 0; itr < 4; ++itr) {
            const size_t idx = base + (size_t)itr * (size_t)(2048 * 256 * 8);
            float4 a = *(const float4*)&xs[idx];
            float4 b = *(const float4*)&xs[idx + 4];
            u16x8 p = { f2bf(a.x), f2bf(a.y), f2bf(a.z), f2bf(a.w),
                        f2bf(b.x), f2bf(b.y), f2bf(b.z), f2bf(b.w) };
            *(u16x8*)&Xb[idx] = p;
        }
    }
}

// ---------------------------------------------------------------------------
// main_gemm_bf16: out[m][n] = leaky( sum_k Xb[m][k]*Wc[n][k] + bcomb[n] )
// m97 structure: 128x128 tile, BK=32, 4 waves (2x2 of 64x64), both operands
// via global_load_lds width-16. Grid = 128*8 = 1024 blocks.
// ---------------------------------------------------------------------------
__global__ __launch_bounds__(256) void main_gemm_bf16(
    const unsigned short* __restrict__ Xb, const unsigned short* __restrict__ Wc,
    const float* __restrict__ bcomb, float* __restrict__ out) {
    __shared__ unsigned short As[128 * 32];
    __shared__ unsigned short Bs[128 * 32];
    const int t = threadIdx.x;
    const int nt = blockIdx.x & 7;
    const int mt = blockIdx.x >> 3;
    const int w = t >> 6, l = t & 63;
    const int wr = (w >> 1) * 64, wcc = (w & 1) * 64;
    const int lr = l & 15, lk = l >> 4;

    f32x4 acc[4][4] = {};

    // staging addressing: lane l loads 16B; row = j*64 + w*16 + (l>>2),
    // col8 = (l&3)*8; LDS dest = wave-uniform base + lane*16B (linear layout).
    const int srow = t >> 2;          // w*16 + (l>>2), 0..63
    const int sc8 = (t & 3) * 8;
    const unsigned short* gA = &Xb[((size_t)(mt * 128) + srow) * KDIM + sc8];
    const unsigned short* gB = &Wc[((size_t)(nt * 128) + srow) * KDIM + sc8];
    unsigned short* lA0 = &As[w * 512];
    unsigned short* lB0 = &Bs[w * 512];

    for (int kt = 0; kt < KDIM / 32; ++kt) {
        #pragma unroll
        for (int j = 0; j < 2; ++j) {
            gload16(gA + (size_t)j * 64 * KDIM + kt * 32, lA0 + j * 2048);
            gload16(gB + (size_t)j * 64 * KDIM + kt * 32, lB0 + j * 2048);
        }
        __syncthreads();  // drains vmcnt -> staged data visible
        bf16x8 af[4], bfr[4];
        #pragma unroll
        for (int fi = 0; fi < 4; ++fi)
            af[fi] = *(bf16x8*)&As[(wr + fi * 16 + lr) * 32 + lk * 8];
        #pragma unroll
        for (int fj = 0; fj < 4; ++fj)
            bfr[fj] = *(bf16x8*)&Bs[(wcc + fj * 16 + lr) * 32 + lk * 8];
        #pragma unroll
        for (int fi = 0; fi < 4; ++fi)
            #pragma unroll
            for (int fj = 0; fj < 4; ++fj)
                acc[fi][fj] = __builtin_amdgcn_mfma_f32_16x16x32_bf16(
                    af[fi], bfr[fj], acc[fi][fj], 0, 0, 0);
        __syncthreads();  // all ds_reads done before next stage overwrites
    }

    #pragma unroll
    for (int fi = 0; fi < 4; ++fi)
        #pragma unroll
        for (int fj = 0; fj < 4; ++fj) {
            const int col = nt * 128 + wcc + fj * 16 + lr;
            const float b = bcomb[col];
            #pragma unroll
            for (int r = 0; r < 4; ++r) {
                const int row = mt * 128 + wr + fi * 16 + lk * 4 + r;
                float v = acc[fi][fj][r] + b;
                out[row * NDIM + col] = v >= 0.f ? v : 0.01f * v;
            }
        }
}

// ---------------------------------------------------------------------------
// Fallback main GEMM (round-1 fused fp32->bf16 path) if ws is too small.
// ---------------------------------------------------------------------------
__global__ __launch_bounds__(256) void main_gemm_f32(
    const float* __restrict__ X, const unsigned short* __restrict__ Wc,
    const float* __restrict__ bcomb, float* __restrict__ out) {
    __shared__ unsigned short As[128 * 32];
    __shared__ unsigned short Bs[128 * 32];
    const int t = threadIdx.x;
    const int nt = blockIdx.x & 7;
    const int mt = blockIdx.x >> 3;
    const int w = t >> 6, l = t & 63;
    const int wr = (w >> 1) * 64, wcc = (w & 1) * 64;
    const int lr = l & 15, lk = l >> 4;

    f32x4 acc[4][4] = {};

    const int arow = t >> 3;
    const int akq = t & 7;
    const int brow = t >> 2;
    const int bc4 = t & 3;

    for (int kt = 0; kt < KDIM / 32; ++kt) {
        float4 av[4];
        #pragma unroll
        for (int j = 0; j < 4; ++j) {
            const int row = j * 32 + arow;
            av[j] = *(const float4*)&X[(mt * 128 + row) * KDIM + kt * 32 + akq * 4];
        }
        __syncthreads();
        #pragma unroll
        for (int j = 0; j < 4; ++j) {
            const int row = j * 32 + arow;
            u16x4 p = { f2bf(av[j].x), f2bf(av[j].y), f2bf(av[j].z), f2bf(av[j].w) };
            *(u16x4*)&As[row * 32 + akq * 4] = p;
        }
        #pragma unroll
        for (int j = 0; j < 2; ++j) {
            const int row = j * 64 + brow;
            const unsigned short* g = &Wc[(nt * 128 + row) * KDIM + kt * 32 + bc4 * 8];
            unsigned short* ldst = &Bs[(j * 256 + w * 64) * 8];
            gload16(g, ldst);
        }
        __syncthreads();
        bf16x8 af[4], bfr[4];
        #pragma unroll
        for (int fi = 0; fi < 4; ++fi)
            af[fi] = *(bf16x8*)&As[(wr + fi * 16 + lr) * 32 + lk * 8];
        #pragma unroll
        for (int fj = 0; fj < 4; ++fj)
            bfr[fj] = *(bf16x8*)&Bs[(wcc + fj * 16 + lr) * 32 + lk * 8];
        #pragma unroll
        for (int fi = 0; fi < 4; ++fi)
            #pragma unroll
            for (int fj = 0; fj < 4; ++fj)
                acc[fi][fj] = __builtin_amdgcn_mfma_f32_16x16x32_bf16(
                    af[fi], bfr[fj], acc[fi][fj], 0, 0, 0);
    }

    #pragma unroll
    for (int fi = 0; fi < 4; ++fi)
        #pragma unroll
        for (int fj = 0; fj < 4; ++fj) {
            const int col = nt * 128 + wcc + fj * 16 + lr;
            const float b = bcomb[col];
            #pragma unroll
            for (int r = 0; r < 4; ++r) {
                const int row = mt * 128 + wr + fi * 16 + lk * 4 + r;
                float v = acc[fi][fj][r] + b;
                out[row * NDIM + col] = v >= 0.f ? v : 0.01f * v;
            }
        }
}

extern "C" void kernel_launch(void* const* d_in, const int* in_sizes, int n_in,
                              void* d_out, int out_size, void* d_ws, size_t ws_size,
                              hipStream_t stream) {
    const float* xs   = (const float*)d_in[0];
    // d_in[1] mask unused: softmax row-sums are exactly 1.
    const float* Wv   = (const float*)d_in[6];
    const float* bv   = (const float*)d_in[7];
    const float* Wlin = (const float*)d_in[8];
    const float* blin = (const float*)d_in[9];

    unsigned short* Wc = (unsigned short*)d_ws;                         // 2 MB
    float* bcomb = (float*)((char*)d_ws + 2097152);                     // 4 KB
    unsigned short* Xb = (unsigned short*)((char*)d_ws + 2101248);      // 32 MB
    float* out = (float*)d_out;

    const size_t NEED = 2101248 + (size_t)M_TOT * KDIM * 2;
    if (ws_size >= NEED) {
        hipLaunchKernelGGL(prep_kernel, dim3(512 + 2048), dim3(256), 0, stream,
                           xs, Wv, bv, Wlin, blin, Wc, bcomb, Xb);
        hipLaunchKernelGGL(main_gemm_bf16, dim3((M_TOT / 128) * (NDIM / 128)),
                           dim3(256), 0, stream, Xb, Wc, bcomb, out);
    } else {
        hipLaunchKernelGGL(prep_kernel, dim3(512), dim3(256), 0, stream,
                           xs, Wv, bv, Wlin, blin, Wc, bcomb, Xb);
        hipLaunchKernelGGL(main_gemm_f32, dim3((M_TOT / 128) * (NDIM / 128)),
                           dim3(256), 0, stream, xs, Wc, bcomb, out);
    }
}

// Round 3
// 86.139 us; speedup vs baseline: 1.4970x; 1.2097x over previous
//
#include <hip/hip_runtime.h>
#include <hip/hip_bf16.h>
#include <stdint.h>

// Problem: B=16, S=1024, IN=1024, OUT=1024.
// Reference collapses: softmax row-sums are exactly 1 (key mask always has >=1
// live column), so out = leaky_relu(xs @ (Wlin@Wv)^T + (Wlin@bv + blin)).
//
// Round 3: main GEMM rebuilt as the 256x256 8-phase-style schedule (T2 LDS
// swizzle + T3/T4 counted vmcnt 4-buffer ring + T5 setprio + XCD swizzle).

#define M_TOT 16384   // B*S
#define KDIM  1024
#define NDIM  1024
#define NT    32      // K-tiles of BK=32

typedef __attribute__((ext_vector_type(8))) short bf16x8;
typedef __attribute__((ext_vector_type(4))) float f32x4;
typedef __attribute__((ext_vector_type(4))) unsigned short u16x4;
typedef __attribute__((ext_vector_type(8))) unsigned short u16x8;

static __device__ __forceinline__ unsigned short f2bf(float f) {
    union { float f; unsigned int u; } v; v.f = f;
    unsigned int u = v.u;
    return (unsigned short)((u + 0x7fffu + ((u >> 16) & 1u)) >> 16);  // RNE
}

static __device__ __forceinline__ void gload16(const void* g, void* l) {
    __builtin_amdgcn_global_load_lds(
        (__attribute__((address_space(1))) void*)(g),
        (__attribute__((address_space(3))) void*)(l), 16, 0, 0);
}

// Involutive LDS byte-swizzle within each 1KB subtile of a [rows][32]bf16
// (64B-stride) region: spread 16-row column-slices across banks (8-way -> 2-way).
static __device__ __forceinline__ int swz(int p) {
    return p ^ (((p >> 9) & 1) << 5) ^ (((p >> 8) & 1) << 4);
}

// ---------------------------------------------------------------------------
// prep_kernel: one dispatch, three roles by blockIdx:
//   [0,256)    : Wc[o][i] = sum_d Wlin[o][d]*Wv[d][i]  (bf16 out, 64x64 tiles)
//   [256,512)  : bcomb[o] = Wlin[o]·bv + blin[o]
//   [512,2560) : Xb = bf16(xs)
// ---------------------------------------------------------------------------
__global__ __launch_bounds__(256) void prep_kernel(
    const float* __restrict__ xs, const float* __restrict__ Wv,
    const float* __restrict__ bv, const float* __restrict__ Wlin,
    const float* __restrict__ blin, unsigned short* __restrict__ Wc,
    float* __restrict__ bcomb, unsigned short* __restrict__ Xb) {
    __shared__ unsigned short Al[64 * 32];
    __shared__ unsigned short Bl[64 * 32];
    const int bid = blockIdx.x;
    const int t = threadIdx.x;

    if (bid < 256) {
        const int ot = bid >> 4;
        const int it = bid & 15;
        const int w = t >> 6, l = t & 63;
        const int wr = (w >> 1) * 32, wc = (w & 1) * 32;
        const int lr = l & 15, lk = l >> 4;

        f32x4 acc[2][2] = {};

        for (int kt = 0; kt < KDIM / 32; ++kt) {
            float4 av[2];
            #pragma unroll
            for (int j = 0; j < 2; ++j) {
                const int row = j * 32 + (t >> 3);
                const int kq = t & 7;
                av[j] = *(const float4*)&Wlin[(ot * 64 + row) * KDIM + kt * 32 + kq * 4];
            }
            float4 bvv[2];
            #pragma unroll
            for (int j = 0; j < 2; ++j) {
                const int d = j * 16 + (t >> 4);
                const int i4 = t & 15;
                bvv[j] = *(const float4*)&Wv[(kt * 32 + d) * NDIM + it * 64 + i4 * 4];
            }
            __syncthreads();
            #pragma unroll
            for (int j = 0; j < 2; ++j) {
                const int row = j * 32 + (t >> 3);
                const int kq = t & 7;
                u16x4 p = { f2bf(av[j].x), f2bf(av[j].y), f2bf(av[j].z), f2bf(av[j].w) };
                *(u16x4*)&Al[row * 32 + kq * 4] = p;
            }
            #pragma unroll
            for (int j = 0; j < 2; ++j) {
                const int d = j * 16 + (t >> 4);
                const int i4 = t & 15;
                Bl[(i4 * 4 + 0) * 32 + d] = f2bf(bvv[j].x);
                Bl[(i4 * 4 + 1) * 32 + d] = f2bf(bvv[j].y);
                Bl[(i4 * 4 + 2) * 32 + d] = f2bf(bvv[j].z);
                Bl[(i4 * 4 + 3) * 32 + d] = f2bf(bvv[j].w);
            }
            __syncthreads();
            bf16x8 af[2], bfr[2];
            #pragma unroll
            for (int fi = 0; fi < 2; ++fi)
                af[fi] = *(bf16x8*)&Al[(wr + fi * 16 + lr) * 32 + lk * 8];
            #pragma unroll
            for (int fj = 0; fj < 2; ++fj)
                bfr[fj] = *(bf16x8*)&Bl[(wc + fj * 16 + lr) * 32 + lk * 8];
            #pragma unroll
            for (int fi = 0; fi < 2; ++fi)
                #pragma unroll
                for (int fj = 0; fj < 2; ++fj)
                    acc[fi][fj] = __builtin_amdgcn_mfma_f32_16x16x32_bf16(
                        af[fi], bfr[fj], acc[fi][fj], 0, 0, 0);
            __syncthreads();
        }
        #pragma unroll
        for (int fi = 0; fi < 2; ++fi)
            #pragma unroll
            for (int fj = 0; fj < 2; ++fj)
                #pragma unroll
                for (int r = 0; r < 4; ++r) {
                    const int o = ot * 64 + wr + fi * 16 + lk * 4 + r;
                    const int i = it * 64 + wc + fj * 16 + lr;
                    Wc[o * KDIM + i] = f2bf(acc[fi][fj][r]);
                }
    } else if (bid < 512) {
        const int wave = t >> 6, lane = t & 63;
        const int o = (bid - 256) * 4 + wave;
        float s = 0.f;
        for (int d = lane; d < KDIM; d += 64) s += Wlin[o * KDIM + d] * bv[d];
        #pragma unroll
        for (int off = 32; off > 0; off >>= 1) s += __shfl_down(s, off, 64);
        if (lane == 0) bcomb[o] = s + blin[o];
    } else {
        const int cb = bid - 512;
        const size_t base = ((size_t)cb * 256 + t) * 8;
        #pragma unroll
        for (int itr = 0; itr < 4; ++itr) {
            const size_t idx = base + (size_t)itr * (size_t)(2048 * 256 * 8);
            float4 a = *(const float4*)&xs[idx];
            float4 b = *(const float4*)&xs[idx + 4];
            u16x8 p = { f2bf(a.x), f2bf(a.y), f2bf(a.z), f2bf(a.w),
                        f2bf(b.x), f2bf(b.y), f2bf(b.z), f2bf(b.w) };
            *(u16x8*)&Xb[idx] = p;
        }
    }
}

// ---------------------------------------------------------------------------
// main_gemm_8p: out = leaky(Xb @ Wc^T + bcomb).
// BM=BN=256, BK=32, 8 waves (2Mx4N), per-wave 128x64 = acc[8][4].
// 4-buffer LDS ring (4 x 32KB = 128KB dynamic), prefetch 3 K-tiles ahead,
// counted vmcnt(8) at K-tile boundaries, 2 phases per K-tile, T2 swizzle,
// T5 setprio, bijective XCD swizzle (grid 256 = 1 block/CU).
// Buffer layout (32KB): A [256][32]bf16 swizzled @0, B [256][32] @16384.
// ---------------------------------------------------------------------------
__global__ __launch_bounds__(512, 2) void main_gemm_8p(
    const unsigned short* __restrict__ Xb, const unsigned short* __restrict__ Wc,
    const float* __restrict__ bcomb, float* __restrict__ out) {
    extern __shared__ char lds[];  // 131072
    const int tid = threadIdx.x;
    const int w = tid >> 6, l = tid & 63;
    const int wm = w >> 2, wn = w & 3;
    const int lr = l & 15, lk = l >> 4;

    // XCD swizzle: 8 consecutive mt-tiles per XCD (256 % 8 == 0, bijective)
    const int swzb = ((blockIdx.x & 7) << 5) + (blockIdx.x >> 3);
    const int mt = swzb >> 2, nt = swzb & 3;

    // reader LDS byte offsets within one 32KB buffer
    int aoff[8], boff[4];
    #pragma unroll
    for (int fi = 0; fi < 8; ++fi)
        aoff[fi] = swz((wm * 128 + fi * 16 + lr) * 64 + lk * 16);
    #pragma unroll
    for (int fj = 0; fj < 4; ++fj)
        boff[fj] = 16384 + swz((wn * 64 + fj * 16 + lr) * 64 + lk * 16);

    // staging: pre-swizzled per-lane global sources (LDS dest stays linear).
    // chunk c covers linear buffer bytes [c*8192, +8192); lane writes q = c*8192
    // + w*1024 + l*16; content there must be logical byte swz(q).
    const char* srcA0; const char* srcA1; const char* srcB0; const char* srcB1;
    {
        int q0 = 0 * 8192 + w * 1024 + l * 16, p0 = swz(q0);
        int q1 = 1 * 8192 + w * 1024 + l * 16, p1 = swz(q1);
        srcA0 = (const char*)Xb + ((size_t)(mt * 256 + (p0 >> 6)) * KDIM) * 2 + (p0 & 63);
        srcA1 = (const char*)Xb + ((size_t)(mt * 256 + (p1 >> 6)) * KDIM) * 2 + (p1 & 63);
        srcB0 = (const char*)Wc + ((size_t)(nt * 256 + (p0 >> 6)) * KDIM) * 2 + (p0 & 63);
        srcB1 = (const char*)Wc + ((size_t)(nt * 256 + (p1 >> 6)) * KDIM) * 2 + (p1 & 63);
    }
    const int ldsw = w * 1024;

    f32x4 acc[8][4] = {};

    // prologue: stage K-tiles 0,1,2 into buffers 0,1,2 (4 loads each)
    #pragma unroll
    for (int pt = 0; pt < 3; ++pt) {
        char* bb = lds + pt * 32768;
        gload16(srcA0 + (size_t)pt * 64, bb + ldsw);
        gload16(srcA1 + (size_t)pt * 64, bb + 8192 + ldsw);
        gload16(srcB0 + (size_t)pt * 64, bb + 16384 + ldsw);
        gload16(srcB1 + (size_t)pt * 64, bb + 24576 + ldsw);
    }

#define KTILE(T, STAGE_EN)                                                     \
    do {                                                                       \
        const char* bufp = lds + (size_t)((T) & 3) * 32768;                    \
        char* nb = lds + (size_t)(((T) + 3) & 3) * 32768;                      \
        /* phase A: stage A-chunks of T+3; read B frags + low A frags */       \
        if (STAGE_EN) {                                                        \
            gload16(srcA0 + (size_t)((T) + 3) * 64, nb + ldsw);                \
            gload16(srcA1 + (size_t)((T) + 3) * 64, nb + 8192 + ldsw);         \
        }                                                                      \
        bf16x8 bfr[4], afr[4];                                                 \
        _Pragma("unroll")                                                      \
        for (int fj = 0; fj < 4; ++fj)                                         \
            bfr[fj] = *(const bf16x8*)(bufp + boff[fj]);                       \
        _Pragma("unroll")                                                      \
        for (int fi = 0; fi < 4; ++fi)                                         \
            afr[fi] = *(const bf16x8*)(bufp + aoff[fi]);                       \
        __builtin_amdgcn_s_barrier();                                          \
        __builtin_amdgcn_s_setprio(1);                                         \
        _Pragma("unroll")                                                      \
        for (int fi = 0; fi < 4; ++fi)                                         \
            _Pragma("unroll")                                                  \
            for (int fj = 0; fj < 4; ++fj)                                     \
                acc[fi][fj] = __builtin_amdgcn_mfma_f32_16x16x32_bf16(         \
                    afr[fi], bfr[fj], acc[fi][fj], 0, 0, 0);                   \
        __builtin_amdgcn_s_setprio(0);                                         \
        __builtin_amdgcn_s_barrier();                                          \
        /* phase B: stage B-chunks of T+3; read high A frags */                \
        if (STAGE_EN) {                                                        \
            gload16(srcB0 + (size_t)((T) + 3) * 64, nb + 16384 + ldsw);        \
            gload16(srcB1 + (size_t)((T) + 3) * 64, nb + 24576 + ldsw);        \
        }                                                                      \
        bf16x8 af2[4];                                                         \
        _Pragma("unroll")                                                      \
        for (int fi = 0; fi < 4; ++fi)                                         \
            af2[fi] = *(const bf16x8*)(bufp + aoff[4 + fi]);                   \
        __builtin_amdgcn_s_barrier();                                          \
        __builtin_amdgcn_s_setprio(1);                                         \
        _Pragma("unroll")                                                      \
        for (int fi = 0; fi < 4; ++fi)                                         \
            _Pragma("unroll")                                                  \
            for (int fj = 0; fj < 4; ++fj)                                     \
                acc[4 + fi][fj] = __builtin_amdgcn_mfma_f32_16x16x32_bf16(     \
                    af2[fi], bfr[fj], acc[4 + fi][fj], 0, 0, 0);               \
        __builtin_amdgcn_s_setprio(0);                                         \
    } while (0)

    // main loop: K-tiles 0..28, always staging tile t+3 (3..31)
    for (int t = 0; t < NT - 3; ++t) {
        asm volatile("s_waitcnt vmcnt(8)" ::: "memory");  // buf[t] resident
        __builtin_amdgcn_s_barrier();
        KTILE(t, 1);
    }
    // tail: 29, 30, 31 (no staging; decreasing counted waits)
    asm volatile("s_waitcnt vmcnt(8)" ::: "memory");
    __builtin_amdgcn_s_barrier();
    KTILE(29, 0);
    asm volatile("s_waitcnt vmcnt(4)" ::: "memory");
    __builtin_amdgcn_s_barrier();
    KTILE(30, 0);
    asm volatile("s_waitcnt vmcnt(0)" ::: "memory");
    __builtin_amdgcn_s_barrier();
    KTILE(31, 0);
#undef KTILE

    // epilogue: + bias, leaky_relu, fp32 store
    #pragma unroll
    for (int fi = 0; fi < 8; ++fi)
        #pragma unroll
        for (int fj = 0; fj < 4; ++fj) {
            const int col = nt * 256 + wn * 64 + fj * 16 + lr;
            const float b = bcomb[col];
            #pragma unroll
            for (int r = 0; r < 4; ++r) {
                const int row = mt * 256 + wm * 128 + fi * 16 + lk * 4 + r;
                float v = acc[fi][fj][r] + b;
                out[(size_t)row * NDIM + col] = v >= 0.f ? v : 0.01f * v;
            }
        }
}

// ---------------------------------------------------------------------------
// Fallback main GEMM (round-2 path) if ws is too small.
// ---------------------------------------------------------------------------
__global__ __launch_bounds__(256) void main_gemm_f32(
    const float* __restrict__ X, const unsigned short* __restrict__ Wc,
    const float* __restrict__ bcomb, float* __restrict__ out) {
    __shared__ unsigned short As[128 * 32];
    __shared__ unsigned short Bs[128 * 32];
    const int t = threadIdx.x;
    const int nt = blockIdx.x & 7;
    const int mt = blockIdx.x >> 3;
    const int w = t >> 6, l = t & 63;
    const int wr = (w >> 1) * 64, wcc = (w & 1) * 64;
    const int lr = l & 15, lk = l >> 4;

    f32x4 acc[4][4] = {};

    const int arow = t >> 3;
    const int akq = t & 7;
    const int brow = t >> 2;
    const int bc4 = t & 3;

    for (int kt = 0; kt < KDIM / 32; ++kt) {
        float4 av[4];
        #pragma unroll
        for (int j = 0; j < 4; ++j) {
            const int row = j * 32 + arow;
            av[j] = *(const float4*)&X[(mt * 128 + row) * KDIM + kt * 32 + akq * 4];
        }
        __syncthreads();
        #pragma unroll
        for (int j = 0; j < 4; ++j) {
            const int row = j * 32 + arow;
            u16x4 p = { f2bf(av[j].x), f2bf(av[j].y), f2bf(av[j].z), f2bf(av[j].w) };
            *(u16x4*)&As[row * 32 + akq * 4] = p;
        }
        #pragma unroll
        for (int j = 0; j < 2; ++j) {
            const int row = j * 64 + brow;
            const unsigned short* g = &Wc[(nt * 128 + row) * KDIM + kt * 32 + bc4 * 8];
            unsigned short* ldst = &Bs[(j * 256 + w * 64) * 8];
            gload16(g, ldst);
        }
        __syncthreads();
        bf16x8 af[4], bfr[4];
        #pragma unroll
        for (int fi = 0; fi < 4; ++fi)
            af[fi] = *(bf16x8*)&As[(wr + fi * 16 + lr) * 32 + lk * 8];
        #pragma unroll
        for (int fj = 0; fj < 4; ++fj)
            bfr[fj] = *(bf16x8*)&Bs[(wcc + fj * 16 + lr) * 32 + lk * 8];
        #pragma unroll
        for (int fi = 0; fi < 4; ++fi)
            #pragma unroll
            for (int fj = 0; fj < 4; ++fj)
                acc[fi][fj] = __builtin_amdgcn_mfma_f32_16x16x32_bf16(
                    af[fi], bfr[fj], acc[fi][fj], 0, 0, 0);
    }

    #pragma unroll
    for (int fi = 0; fi < 4; ++fi)
        #pragma unroll
        for (int fj = 0; fj < 4; ++fj) {
            const int col = nt * 128 + wcc + fj * 16 + lr;
            const float b = bcomb[col];
            #pragma unroll
            for (int r = 0; r < 4; ++r) {
                const int row = mt * 128 + wr + fi * 16 + lk * 4 + r;
                float v = acc[fi][fj][r] + b;
                out[row * NDIM + col] = v >= 0.f ? v : 0.01f * v;
            }
        }
}

extern "C" void kernel_launch(void* const* d_in, const int* in_sizes, int n_in,
                              void* d_out, int out_size, void* d_ws, size_t ws_size,
                              hipStream_t stream) {
    const float* xs   = (const float*)d_in[0];
    // d_in[1] mask unused: softmax row-sums are exactly 1.
    const float* Wv   = (const float*)d_in[6];
    const float* bv   = (const float*)d_in[7];
    const float* Wlin = (const float*)d_in[8];
    const float* blin = (const float*)d_in[9];

    unsigned short* Wc = (unsigned short*)d_ws;                         // 2 MB
    float* bcomb = (float*)((char*)d_ws + 2097152);                     // 4 KB
    unsigned short* Xb = (unsigned short*)((char*)d_ws + 2101248);      // 32 MB
    float* out = (float*)d_out;

    const size_t NEED = 2101248 + (size_t)M_TOT * KDIM * 2;
    if (ws_size >= NEED) {
        (void)hipFuncSetAttribute((const void*)main_gemm_8p,
                                  hipFuncAttributeMaxDynamicSharedMemorySize,
                                  131072);
        hipLaunchKernelGGL(prep_kernel, dim3(512 + 2048), dim3(256), 0, stream,
                           xs, Wv, bv, Wlin, blin, Wc, bcomb, Xb);
        hipLaunchKernelGGL(main_gemm_8p, dim3(256), dim3(512), 131072, stream,
                           Xb, Wc, bcomb, out);
    } else {
        hipLaunchKernelGGL(prep_kernel, dim3(512), dim3(256), 0, stream,
                           xs, Wv, bv, Wlin, blin, Wc, bcomb, Xb);
        hipLaunchKernelGGL(main_gemm_f32, dim3((M_TOT / 128) * (NDIM / 128)),
                           dim3(256), 0, stream, xs, Wc, bcomb, out);
    }
}

// Round 4
// 83.096 us; speedup vs baseline: 1.5518x; 1.0366x over previous
//
#include <hip/hip_runtime.h>
#include <hip/hip_bf16.h>
#include <stdint.h>

// Problem: B=16, S=1024, IN=1024, OUT=1024.
// Reference collapses: softmax row-sums are exactly 1 (key mask always has >=1
// live column), so out = leaky_relu(xs @ (Wlin@Wv)^T + (Wlin@bv + blin)).
//
// Round 4: prep restructured. Round-3's fused Wcomb GEMM transposed Wv via
// scalar LDS writes (16-32-way bank conflicts, 8.4M cycles) making prep the
// 55us long pole. Now: prep0 = conflict-free tile-transpose Wv->bf16 +
// Wlin->bf16 + bias fold (scratch in d_out); prep1 = 64-block pure-bf16
// wcomb GEMM overlapped with 2048-block xs->bf16 conversion.

#define M_TOT 16384   // B*S
#define KDIM  1024
#define NDIM  1024
#define NT    32      // K-tiles of BK=32 in main GEMM

typedef __attribute__((ext_vector_type(8))) short bf16x8;
typedef __attribute__((ext_vector_type(4))) float f32x4;
typedef __attribute__((ext_vector_type(4))) unsigned short u16x4;
typedef __attribute__((ext_vector_type(8))) unsigned short u16x8;

static __device__ __forceinline__ unsigned short f2bf(float f) {
    union { float f; unsigned int u; } v; v.f = f;
    unsigned int u = v.u;
    return (unsigned short)((u + 0x7fffu + ((u >> 16) & 1u)) >> 16);  // RNE
}

static __device__ __forceinline__ void gload16(const void* g, void* l) {
    __builtin_amdgcn_global_load_lds(
        (__attribute__((address_space(1))) void*)(g),
        (__attribute__((address_space(3))) void*)(l), 16, 0, 0);
}

// Involutive LDS byte-swizzle within 1KB subtiles of a [rows][32]bf16 region.
static __device__ __forceinline__ int swz(int p) {
    return p ^ (((p >> 9) & 1) << 5) ^ (((p >> 8) & 1) << 4);
}

// ---------------------------------------------------------------------------
// prep0: [0,256) transpose Wv[d][i] -> Wvt[i][d] bf16 (64x64 tiles, padded
//        fp32 LDS, conflict-free); [256,512) Wlin -> Wlb bf16; [512,768) bias.
// ---------------------------------------------------------------------------
__global__ __launch_bounds__(256) void prep0_kernel(
    const float* __restrict__ Wv, const float* __restrict__ Wlin,
    const float* __restrict__ bv, const float* __restrict__ blin,
    unsigned short* __restrict__ Wvt, unsigned short* __restrict__ Wlb,
    float* __restrict__ bcomb) {
    __shared__ float Tl[64 * 65];
    const int bid = blockIdx.x;
    const int t = threadIdx.x;

    if (bid < 256) {
        const int dt = bid >> 4;   // d tile
        const int it = bid & 15;   // i tile
        const int r = t >> 2;      // 0..63
        const int c0 = (t & 3) * 16;
        #pragma unroll
        for (int u = 0; u < 4; ++u) {
            float4 v = *(const float4*)&Wv[((size_t)(dt * 64 + r)) * NDIM + it * 64 + c0 + 4 * u];
            Tl[r * 65 + c0 + 4 * u + 0] = v.x;
            Tl[r * 65 + c0 + 4 * u + 1] = v.y;
            Tl[r * 65 + c0 + 4 * u + 2] = v.z;
            Tl[r * 65 + c0 + 4 * u + 3] = v.w;
        }
        __syncthreads();
        const int i = t >> 2;        // local out row
        const int dq = (t & 3) * 16; // d chunk
        float v[16];
        #pragma unroll
        for (int u = 0; u < 16; ++u) v[u] = Tl[(dq + u) * 65 + i];
        u16x8 p0 = { f2bf(v[0]), f2bf(v[1]), f2bf(v[2]), f2bf(v[3]),
                     f2bf(v[4]), f2bf(v[5]), f2bf(v[6]), f2bf(v[7]) };
        u16x8 p1 = { f2bf(v[8]), f2bf(v[9]), f2bf(v[10]), f2bf(v[11]),
                     f2bf(v[12]), f2bf(v[13]), f2bf(v[14]), f2bf(v[15]) };
        unsigned short* dst = &Wvt[((size_t)(it * 64 + i)) * KDIM + dt * 64 + dq];
        *(u16x8*)dst = p0;
        *(u16x8*)(dst + 8) = p1;
    } else if (bid < 512) {
        const size_t idx = (((size_t)(bid - 256)) * 256 + t) * 16;
        float4 a = *(const float4*)&Wlin[idx];
        float4 b = *(const float4*)&Wlin[idx + 4];
        float4 c = *(const float4*)&Wlin[idx + 8];
        float4 d = *(const float4*)&Wlin[idx + 12];
        u16x8 p0 = { f2bf(a.x), f2bf(a.y), f2bf(a.z), f2bf(a.w),
                     f2bf(b.x), f2bf(b.y), f2bf(b.z), f2bf(b.w) };
        u16x8 p1 = { f2bf(c.x), f2bf(c.y), f2bf(c.z), f2bf(c.w),
                     f2bf(d.x), f2bf(d.y), f2bf(d.z), f2bf(d.w) };
        *(u16x8*)&Wlb[idx] = p0;
        *(u16x8*)&Wlb[idx + 8] = p1;
    } else {
        const int wave = t >> 6, lane = t & 63;
        const int o = (bid - 512) * 4 + wave;
        float s = 0.f;
        for (int d = lane; d < KDIM; d += 64) s += Wlin[o * KDIM + d] * bv[d];
        #pragma unroll
        for (int off = 32; off > 0; off >>= 1) s += __shfl_down(s, off, 64);
        if (lane == 0) bcomb[o] = s + blin[o];
    }
}

// ---------------------------------------------------------------------------
// prep1: blocks [0,64): Wc = Wlb @ Wvt^T (1024^3 bf16 GEMM, 128x128 tiles,
//        m97 structure, both operands global_load_lds). Blocks [64,2112):
//        Xb = bf16(xs). The small GEMM hides under the conversion.
// ---------------------------------------------------------------------------
__global__ __launch_bounds__(256) void prep1_kernel(
    const unsigned short* __restrict__ Wlb, const unsigned short* __restrict__ Wvt,
    const float* __restrict__ xs, unsigned short* __restrict__ Wc,
    unsigned short* __restrict__ Xb) {
    __shared__ unsigned short As[128 * 32];
    __shared__ unsigned short Bs[128 * 32];
    const int bid = blockIdx.x;
    const int t = threadIdx.x;

    if (bid >= 64) {
        // ---- xs -> bf16 ----
        const size_t base = (((size_t)(bid - 64)) * 256 + t) * 8;
        #pragma unroll
        for (int itr = 0; itr < 4; ++itr) {
            const size_t idx = base + (size_t)itr * (size_t)(2048 * 256 * 8);
            float4 a = *(const float4*)&xs[idx];
            float4 b = *(const float4*)&xs[idx + 4];
            u16x8 p = { f2bf(a.x), f2bf(a.y), f2bf(a.z), f2bf(a.w),
                        f2bf(b.x), f2bf(b.y), f2bf(b.z), f2bf(b.w) };
            *(u16x8*)&Xb[idx] = p;
        }
        return;
    }

    // ---- wcomb GEMM: Wc[o][i] = sum_d Wlb[o][d] * Wvt[i][d] ----
    const int nt8 = bid & 7;
    const int mt8 = bid >> 3;
    const int w = t >> 6, l = t & 63;
    const int wr = (w >> 1) * 64, wcc = (w & 1) * 64;
    const int lr = l & 15, lk = l >> 4;

    f32x4 acc[4][4] = {};

    const int srow = t >> 2;
    const int sc8 = (t & 3) * 8;
    const unsigned short* gA = &Wlb[((size_t)(mt8 * 128) + srow) * KDIM + sc8];
    const unsigned short* gB = &Wvt[((size_t)(nt8 * 128) + srow) * KDIM + sc8];
    unsigned short* lA0 = &As[w * 512];
    unsigned short* lB0 = &Bs[w * 512];

    for (int kt = 0; kt < KDIM / 32; ++kt) {
        #pragma unroll
        for (int j = 0; j < 2; ++j) {
            gload16(gA + (size_t)j * 64 * KDIM + kt * 32, lA0 + j * 2048);
            gload16(gB + (size_t)j * 64 * KDIM + kt * 32, lB0 + j * 2048);
        }
        __syncthreads();
        bf16x8 af[4], bfr[4];
        #pragma unroll
        for (int fi = 0; fi < 4; ++fi)
            af[fi] = *(bf16x8*)&As[(wr + fi * 16 + lr) * 32 + lk * 8];
        #pragma unroll
        for (int fj = 0; fj < 4; ++fj)
            bfr[fj] = *(bf16x8*)&Bs[(wcc + fj * 16 + lr) * 32 + lk * 8];
        #pragma unroll
        for (int fi = 0; fi < 4; ++fi)
            #pragma unroll
            for (int fj = 0; fj < 4; ++fj)
                acc[fi][fj] = __builtin_amdgcn_mfma_f32_16x16x32_bf16(
                    af[fi], bfr[fj], acc[fi][fj], 0, 0, 0);
        __syncthreads();
    }

    #pragma unroll
    for (int fi = 0; fi < 4; ++fi)
        #pragma unroll
        for (int fj = 0; fj < 4; ++fj) {
            const int col = nt8 * 128 + wcc + fj * 16 + lr;
            #pragma unroll
            for (int r = 0; r < 4; ++r) {
                const int row = mt8 * 128 + wr + fi * 16 + lk * 4 + r;
                Wc[(size_t)row * KDIM + col] = f2bf(acc[fi][fj][r]);
            }
        }
}

// ---------------------------------------------------------------------------
// main_gemm_8p: out = leaky(Xb @ Wc^T + bcomb).  (unchanged from round 3)
// BM=BN=256, BK=32, 8 waves (2Mx4N), 4-buffer LDS ring, counted vmcnt(8),
// T2 swizzle, T5 setprio, bijective XCD swizzle; grid 256 = 1 block/CU.
// ---------------------------------------------------------------------------
__global__ __launch_bounds__(512, 2) void main_gemm_8p(
    const unsigned short* __restrict__ Xb, const unsigned short* __restrict__ Wc,
    const float* __restrict__ bcomb, float* __restrict__ out) {
    extern __shared__ char lds[];  // 131072
    const int tid = threadIdx.x;
    const int w = tid >> 6, l = tid & 63;
    const int wm = w >> 2, wn = w & 3;
    const int lr = l & 15, lk = l >> 4;

    const int swzb = ((blockIdx.x & 7) << 5) + (blockIdx.x >> 3);
    const int mt = swzb >> 2, nt = swzb & 3;

    int aoff[8], boff[4];
    #pragma unroll
    for (int fi = 0; fi < 8; ++fi)
        aoff[fi] = swz((wm * 128 + fi * 16 + lr) * 64 + lk * 16);
    #pragma unroll
    for (int fj = 0; fj < 4; ++fj)
        boff[fj] = 16384 + swz((wn * 64 + fj * 16 + lr) * 64 + lk * 16);

    const char* srcA0; const char* srcA1; const char* srcB0; const char* srcB1;
    {
        int q0 = 0 * 8192 + w * 1024 + l * 16, p0 = swz(q0);
        int q1 = 1 * 8192 + w * 1024 + l * 16, p1 = swz(q1);
        srcA0 = (const char*)Xb + ((size_t)(mt * 256 + (p0 >> 6)) * KDIM) * 2 + (p0 & 63);
        srcA1 = (const char*)Xb + ((size_t)(mt * 256 + (p1 >> 6)) * KDIM) * 2 + (p1 & 63);
        srcB0 = (const char*)Wc + ((size_t)(nt * 256 + (p0 >> 6)) * KDIM) * 2 + (p0 & 63);
        srcB1 = (const char*)Wc + ((size_t)(nt * 256 + (p1 >> 6)) * KDIM) * 2 + (p1 & 63);
    }
    const int ldsw = w * 1024;

    f32x4 acc[8][4] = {};

    #pragma unroll
    for (int pt = 0; pt < 3; ++pt) {
        char* bb = lds + pt * 32768;
        gload16(srcA0 + (size_t)pt * 64, bb + ldsw);
        gload16(srcA1 + (size_t)pt * 64, bb + 8192 + ldsw);
        gload16(srcB0 + (size_t)pt * 64, bb + 16384 + ldsw);
        gload16(srcB1 + (size_t)pt * 64, bb + 24576 + ldsw);
    }

#define KTILE(T, STAGE_EN)                                                     \
    do {                                                                       \
        const char* bufp = lds + (size_t)((T) & 3) * 32768;                    \
        char* nb = lds + (size_t)(((T) + 3) & 3) * 32768;                      \
        if (STAGE_EN) {                                                        \
            gload16(srcA0 + (size_t)((T) + 3) * 64, nb + ldsw);                \
            gload16(srcA1 + (size_t)((T) + 3) * 64, nb + 8192 + ldsw);         \
        }                                                                      \
        bf16x8 bfr[4], afr[4];                                                 \
        _Pragma("unroll")                                                      \
        for (int fj = 0; fj < 4; ++fj)                                         \
            bfr[fj] = *(const bf16x8*)(bufp + boff[fj]);                       \
        _Pragma("unroll")                                                      \
        for (int fi = 0; fi < 4; ++fi)                                         \
            afr[fi] = *(const bf16x8*)(bufp + aoff[fi]);                       \
        __builtin_amdgcn_s_barrier();                                          \
        __builtin_amdgcn_s_setprio(1);                                         \
        _Pragma("unroll")                                                      \
        for (int fi = 0; fi < 4; ++fi)                                         \
            _Pragma("unroll")                                                  \
            for (int fj = 0; fj < 4; ++fj)                                     \
                acc[fi][fj] = __builtin_amdgcn_mfma_f32_16x16x32_bf16(         \
                    afr[fi], bfr[fj], acc[fi][fj], 0, 0, 0);                   \
        __builtin_amdgcn_s_setprio(0);                                         \
        __builtin_amdgcn_s_barrier();                                          \
        if (STAGE_EN) {                                                        \
            gload16(srcB0 + (size_t)((T) + 3) * 64, nb + 16384 + ldsw);        \
            gload16(srcB1 + (size_t)((T) + 3) * 64, nb + 24576 + ldsw);        \
        }                                                                      \
        bf16x8 af2[4];                                                         \
        _Pragma("unroll")                                                      \
        for (int fi = 0; fi < 4; ++fi)                                         \
            af2[fi] = *(const bf16x8*)(bufp + aoff[4 + fi]);                   \
        __builtin_amdgcn_s_barrier();                                          \
        __builtin_amdgcn_s_setprio(1);                                         \
        _Pragma("unroll")                                                      \
        for (int fi = 0; fi < 4; ++fi)                                         \
            _Pragma("unroll")                                                  \
            for (int fj = 0; fj < 4; ++fj)                                     \
                acc[4 + fi][fj] = __builtin_amdgcn_mfma_f32_16x16x32_bf16(     \
                    af2[fi], bfr[fj], acc[4 + fi][fj], 0, 0, 0);               \
        __builtin_amdgcn_s_setprio(0);                                         \
    } while (0)

    for (int t = 0; t < NT - 3; ++t) {
        asm volatile("s_waitcnt vmcnt(8)" ::: "memory");
        __builtin_amdgcn_s_barrier();
        KTILE(t, 1);
    }
    asm volatile("s_waitcnt vmcnt(8)" ::: "memory");
    __builtin_amdgcn_s_barrier();
    KTILE(29, 0);
    asm volatile("s_waitcnt vmcnt(4)" ::: "memory");
    __builtin_amdgcn_s_barrier();
    KTILE(30, 0);
    asm volatile("s_waitcnt vmcnt(0)" ::: "memory");
    __builtin_amdgcn_s_barrier();
    KTILE(31, 0);
#undef KTILE

    #pragma unroll
    for (int fi = 0; fi < 8; ++fi)
        #pragma unroll
        for (int fj = 0; fj < 4; ++fj) {
            const int col = nt * 256 + wn * 64 + fj * 16 + lr;
            const float b = bcomb[col];
            #pragma unroll
            for (int r = 0; r < 4; ++r) {
                const int row = mt * 256 + wm * 128 + fi * 16 + lk * 4 + r;
                float v = acc[fi][fj][r] + b;
                out[(size_t)row * NDIM + col] = v >= 0.f ? v : 0.01f * v;
            }
        }
}

// ---------------------------------------------------------------------------
// Fallback main GEMM (fused fp32->bf16 A path) if ws is too small for Xb.
// ---------------------------------------------------------------------------
__global__ __launch_bounds__(256) void main_gemm_f32(
    const float* __restrict__ X, const unsigned short* __restrict__ Wc,
    const float* __restrict__ bcomb, float* __restrict__ out) {
    __shared__ unsigned short As[128 * 32];
    __shared__ unsigned short Bs[128 * 32];
    const int t = threadIdx.x;
    const int nt = blockIdx.x & 7;
    const int mt = blockIdx.x >> 3;
    const int w = t >> 6, l = t & 63;
    const int wr = (w >> 1) * 64, wcc = (w & 1) * 64;
    const int lr = l & 15, lk = l >> 4;

    f32x4 acc[4][4] = {};

    const int arow = t >> 3;
    const int akq = t & 7;
    const int brow = t >> 2;
    const int bc4 = t & 3;

    for (int kt = 0; kt < KDIM / 32; ++kt) {
        float4 av[4];
        #pragma unroll
        for (int j = 0; j < 4; ++j) {
            const int row = j * 32 + arow;
            av[j] = *(const float4*)&X[(mt * 128 + row) * KDIM + kt * 32 + akq * 4];
        }
        __syncthreads();
        #pragma unroll
        for (int j = 0; j < 4; ++j) {
            const int row = j * 32 + arow;
            u16x4 p = { f2bf(av[j].x), f2bf(av[j].y), f2bf(av[j].z), f2bf(av[j].w) };
            *(u16x4*)&As[row * 32 + akq * 4] = p;
        }
        #pragma unroll
        for (int j = 0; j < 2; ++j) {
            const int row = j * 64 + brow;
            const unsigned short* g = &Wc[(nt * 128 + row) * KDIM + kt * 32 + bc4 * 8];
            unsigned short* ldst = &Bs[(j * 256 + w * 64) * 8];
            gload16(g, ldst);
        }
        __syncthreads();
        bf16x8 af[4], bfr[4];
        #pragma unroll
        for (int fi = 0; fi < 4; ++fi)
            af[fi] = *(bf16x8*)&As[(wr + fi * 16 + lr) * 32 + lk * 8];
        #pragma unroll
        for (int fj = 0; fj < 4; ++fj)
            bfr[fj] = *(bf16x8*)&Bs[(wcc + fj * 16 + lr) * 32 + lk * 8];
        #pragma unroll
        for (int fi = 0; fi < 4; ++fi)
            #pragma unroll
            for (int fj = 0; fj < 4; ++fj)
                acc[fi][fj] = __builtin_amdgcn_mfma_f32_16x16x32_bf16(
                    af[fi], bfr[fj], acc[fi][fj], 0, 0, 0);
    }

    #pragma unroll
    for (int fi = 0; fi < 4; ++fi)
        #pragma unroll
        for (int fj = 0; fj < 4; ++fj) {
            const int col = nt * 128 + wcc + fj * 16 + lr;
            const float b = bcomb[col];
            #pragma unroll
            for (int r = 0; r < 4; ++r) {
                const int row = mt * 128 + wr + fi * 16 + lk * 4 + r;
                float v = acc[fi][fj][r] + b;
                out[row * NDIM + col] = v >= 0.f ? v : 0.01f * v;
            }
        }
}

extern "C" void kernel_launch(void* const* d_in, const int* in_sizes, int n_in,
                              void* d_out, int out_size, void* d_ws, size_t ws_size,
                              hipStream_t stream) {
    const float* xs   = (const float*)d_in[0];
    // d_in[1] mask unused: softmax row-sums are exactly 1.
    const float* Wv   = (const float*)d_in[6];
    const float* bv   = (const float*)d_in[7];
    const float* Wlin = (const float*)d_in[8];
    const float* blin = (const float*)d_in[9];

    unsigned short* Wc = (unsigned short*)d_ws;                         // 2 MB
    float* bcomb = (float*)((char*)d_ws + 2097152);                     // 4 KB
    unsigned short* Xb = (unsigned short*)((char*)d_ws + 2101248);      // 32 MB
    float* out = (float*)d_out;

    // transient scratch in d_out (64 MB, fully overwritten by the final GEMM)
    unsigned short* Wvt = (unsigned short*)d_out;                       // 2 MB
    unsigned short* Wlb = (unsigned short*)((char*)d_out + 2097152);    // 2 MB

    const size_t NEED = 2101248 + (size_t)M_TOT * KDIM * 2;
    if (ws_size >= NEED) {
        (void)hipFuncSetAttribute((const void*)main_gemm_8p,
                                  hipFuncAttributeMaxDynamicSharedMemorySize,
                                  131072);
        hipLaunchKernelGGL(prep0_kernel, dim3(768), dim3(256), 0, stream,
                           Wv, Wlin, bv, blin, Wvt, Wlb, bcomb);
        hipLaunchKernelGGL(prep1_kernel, dim3(64 + 2048), dim3(256), 0, stream,
                           Wlb, Wvt, xs, Wc, Xb);
        hipLaunchKernelGGL(main_gemm_8p, dim3(256), dim3(512), 131072, stream,
                           Xb, Wc, bcomb, out);
    } else {
        hipLaunchKernelGGL(prep0_kernel, dim3(768), dim3(256), 0, stream,
                           Wv, Wlin, bv, blin, Wvt, Wlb, bcomb);
        hipLaunchKernelGGL(prep1_kernel, dim3(64), dim3(256), 0, stream,
                           Wlb, Wvt, xs, Wc, Xb);
        hipLaunchKernelGGL(main_gemm_f32, dim3((M_TOT / 128) * (NDIM / 128)),
                           dim3(256), 0, stream, xs, Wc, bcomb, out);
    }
}

// Round 5
// 79.978 us; speedup vs baseline: 1.6123x; 1.0390x over previous
//
#include <hip/hip_runtime.h>
#include <hip/hip_bf16.h>
#include <stdint.h>

// Problem: B=16, S=1024, IN=1024, OUT=1024.
// Reference collapses: softmax row-sums are exactly 1 (key mask always has >=1
// live column), so out = leaky_relu(xs @ (Wlin@Wv)^T + (Wlin@bv + blin)).
//
// Round 5: eliminate the xs->bf16 conversion pass (was 28us / 96MB traffic).
// Main GEMM now reads xs fp32 directly, converts in registers (T14 reg-staged
// A -> swizzled ds_write), B (Wc, L2-resident) via pre-swizzled global_load_lds.
// BK=64 double-buffered, 4 barrier-phases per K-tile, setprio, XCD swizzle.

#define M_TOT 16384   // B*S
#define KDIM  1024
#define NDIM  1024
#define NKT   16      // K-tiles of BK=64 in main GEMM

typedef __attribute__((ext_vector_type(8))) short bf16x8;
typedef __attribute__((ext_vector_type(4))) float f32x4;
typedef __attribute__((ext_vector_type(4))) unsigned short u16x4;
typedef __attribute__((ext_vector_type(8))) unsigned short u16x8;

static __device__ __forceinline__ unsigned short f2bf(float f) {
    union { float f; unsigned int u; } v; v.f = f;
    unsigned int u = v.u;
    return (unsigned short)((u + 0x7fffu + ((u >> 16) & 1u)) >> 16);  // RNE
}

static __device__ __forceinline__ u16x8 pack8(float4 a, float4 b) {
    u16x8 p = { f2bf(a.x), f2bf(a.y), f2bf(a.z), f2bf(a.w),
                f2bf(b.x), f2bf(b.y), f2bf(b.z), f2bf(b.w) };
    return p;
}

static __device__ __forceinline__ void gload16(const void* g, void* l) {
    __builtin_amdgcn_global_load_lds(
        (__attribute__((address_space(1))) void*)(g),
        (__attribute__((address_space(3))) void*)(l), 16, 0, 0);
}

// Involutive byte-swizzle for [rows][64]bf16 (128B-stride) LDS tiles: XOR row
// bits (7-9) into 16B-slot bits (4-6). 16-way column conflict -> free 2-way.
static __device__ __forceinline__ int swz128(int p) {
    return p ^ (((p >> 7) & 7) << 4);
}

// ---------------------------------------------------------------------------
// prep0: [0,256) transpose Wv[d][i] -> Wvt[i][d] bf16 (64x64 tiles, padded
//        fp32 LDS); [256,512) Wlin -> Wlb bf16; [512,768) bias fold.
// ---------------------------------------------------------------------------
__global__ __launch_bounds__(256) void prep0_kernel(
    const float* __restrict__ Wv, const float* __restrict__ Wlin,
    const float* __restrict__ bv, const float* __restrict__ blin,
    unsigned short* __restrict__ Wvt, unsigned short* __restrict__ Wlb,
    float* __restrict__ bcomb) {
    __shared__ float Tl[64 * 65];
    const int bid = blockIdx.x;
    const int t = threadIdx.x;

    if (bid < 256) {
        const int dt = bid >> 4;
        const int it = bid & 15;
        const int r = t >> 2;
        const int c0 = (t & 3) * 16;
        #pragma unroll
        for (int u = 0; u < 4; ++u) {
            float4 v = *(const float4*)&Wv[((size_t)(dt * 64 + r)) * NDIM + it * 64 + c0 + 4 * u];
            Tl[r * 65 + c0 + 4 * u + 0] = v.x;
            Tl[r * 65 + c0 + 4 * u + 1] = v.y;
            Tl[r * 65 + c0 + 4 * u + 2] = v.z;
            Tl[r * 65 + c0 + 4 * u + 3] = v.w;
        }
        __syncthreads();
        const int i = t >> 2;
        const int dq = (t & 3) * 16;
        float v[16];
        #pragma unroll
        for (int u = 0; u < 16; ++u) v[u] = Tl[(dq + u) * 65 + i];
        u16x8 p0 = { f2bf(v[0]), f2bf(v[1]), f2bf(v[2]), f2bf(v[3]),
                     f2bf(v[4]), f2bf(v[5]), f2bf(v[6]), f2bf(v[7]) };
        u16x8 p1 = { f2bf(v[8]), f2bf(v[9]), f2bf(v[10]), f2bf(v[11]),
                     f2bf(v[12]), f2bf(v[13]), f2bf(v[14]), f2bf(v[15]) };
        unsigned short* dst = &Wvt[((size_t)(it * 64 + i)) * KDIM + dt * 64 + dq];
        *(u16x8*)dst = p0;
        *(u16x8*)(dst + 8) = p1;
    } else if (bid < 512) {
        const size_t idx = (((size_t)(bid - 256)) * 256 + t) * 16;
        float4 a = *(const float4*)&Wlin[idx];
        float4 b = *(const float4*)&Wlin[idx + 4];
        float4 c = *(const float4*)&Wlin[idx + 8];
        float4 d = *(const float4*)&Wlin[idx + 12];
        *(u16x8*)&Wlb[idx] = pack8(a, b);
        *(u16x8*)&Wlb[idx + 8] = pack8(c, d);
    } else {
        const int wave = t >> 6, lane = t & 63;
        const int o = (bid - 512) * 4 + wave;
        float s = 0.f;
        for (int d = lane; d < KDIM; d += 64) s += Wlin[o * KDIM + d] * bv[d];
        #pragma unroll
        for (int off = 32; off > 0; off >>= 1) s += __shfl_down(s, off, 64);
        if (lane == 0) bcomb[o] = s + blin[o];
    }
}

// ---------------------------------------------------------------------------
// wcomb: Wc[o][i] = sum_d Wlb[o][d] * Wvt[i][d]. 64x64 tiles, 256 blocks
// (full chip), 4 waves (2x2 of 32x32), both operands via global_load_lds.
// ---------------------------------------------------------------------------
__global__ __launch_bounds__(256) void wcomb_kernel(
    const unsigned short* __restrict__ Wlb, const unsigned short* __restrict__ Wvt,
    unsigned short* __restrict__ Wc) {
    __shared__ unsigned short As[64 * 32];
    __shared__ unsigned short Bs[64 * 32];
    const int t = threadIdx.x;
    const int ot = blockIdx.x >> 4;
    const int it = blockIdx.x & 15;
    const int w = t >> 6, l = t & 63;
    const int wr = (w >> 1) * 32, wc = (w & 1) * 32;
    const int lr = l & 15, lk = l >> 4;

    f32x4 acc[2][2] = {};

    const unsigned short* gA = &Wlb[((size_t)(ot * 64 + (t >> 2))) * KDIM + (t & 3) * 8];
    const unsigned short* gB = &Wvt[((size_t)(it * 64 + (t >> 2))) * KDIM + (t & 3) * 8];
    unsigned short* lA = &As[w * 512];
    unsigned short* lB = &Bs[w * 512];

    for (int kt = 0; kt < KDIM / 32; ++kt) {
        gload16(gA + kt * 32, lA);
        gload16(gB + kt * 32, lB);
        __syncthreads();
        bf16x8 af[2], bfr[2];
        #pragma unroll
        for (int fi = 0; fi < 2; ++fi)
            af[fi] = *(bf16x8*)&As[(wr + fi * 16 + lr) * 32 + lk * 8];
        #pragma unroll
        for (int fj = 0; fj < 2; ++fj)
            bfr[fj] = *(bf16x8*)&Bs[(wc + fj * 16 + lr) * 32 + lk * 8];
        #pragma unroll
        for (int fi = 0; fi < 2; ++fi)
            #pragma unroll
            for (int fj = 0; fj < 2; ++fj)
                acc[fi][fj] = __builtin_amdgcn_mfma_f32_16x16x32_bf16(
                    af[fi], bfr[fj], acc[fi][fj], 0, 0, 0);
        __syncthreads();
    }
    #pragma unroll
    for (int fi = 0; fi < 2; ++fi)
        #pragma unroll
        for (int fj = 0; fj < 2; ++fj)
            #pragma unroll
            for (int r = 0; r < 4; ++r) {
                const int o = ot * 64 + wr + fi * 16 + lk * 4 + r;
                const int i = it * 64 + wc + fj * 16 + lr;
                Wc[(size_t)o * KDIM + i] = f2bf(acc[fi][fj][r]);
            }
}

// ---------------------------------------------------------------------------
// main_fused: out = leaky(bf16(xs) @ Wc^T + bcomb), fp32 A converted in-kernel.
// BM=BN=256, BK=64, 8 waves (2Mx4N), per-wave 128x64 = acc[8][4].
// LDS 131072 = 2 bufs x (A 32KB + B 32KB), swz128 both tiles.
// 4 phases per K-tile; only vmcnt drain waits 4 L2-hot B gloads.
// Grid 256 = 1 block/CU, bijective XCD swizzle (4 nt-blocks/mt share an XCD).
// ---------------------------------------------------------------------------
__global__ __launch_bounds__(512, 2) void main_fused(
    const float* __restrict__ xs, const unsigned short* __restrict__ Wc,
    const float* __restrict__ bcomb, float* __restrict__ out) {
    extern __shared__ char lds[];  // 131072
    const int tid = threadIdx.x;
    const int w = tid >> 6, l = tid & 63;
    const int wm = w >> 2, wn = w & 3;
    const int lr = l & 15, lk = l >> 4;

    // XCD swizzle: blocks sharing mt (nt=0..3) land on one XCD for xs L2 reuse
    const int swzb = ((blockIdx.x & 7) << 5) + (blockIdx.x >> 3);
    const int mt = swzb >> 2, nt = swzb & 3;

    // reader LDS byte offsets (kh=0); kh=1 is ^64 (bit 6 untouched by swz128)
    int aoff[8], boff[4];
    #pragma unroll
    for (int fi = 0; fi < 8; ++fi)
        aoff[fi] = swz128((wm * 128 + fi * 16 + lr) * 128 + lk * 16);
    #pragma unroll
    for (int fj = 0; fj < 4; ++fj)
        boff[fj] = 32768 + swz128((wn * 64 + fj * 16 + lr) * 128 + lk * 16);

    // A staging: thread handles 4 chunks (row = j*64 + tid>>3, kslot = tid&7)
    const float* gA[4];
    int awr[4];
    #pragma unroll
    for (int j = 0; j < 4; ++j) {
        const int row = j * 64 + (tid >> 3);
        gA[j] = xs + ((size_t)(mt * 256 + row)) * KDIM + (tid & 7) * 8;
        awr[j] = swz128(row * 128 + (tid & 7) * 16);
    }
    // B staging: 4 chunks, pre-swizzled global source, linear gload_lds dest
    const char* gB[4];
    #pragma unroll
    for (int j = 0; j < 4; ++j) {
        const int q = j * 8192 + w * 1024 + l * 16;
        const int p = swz128(q);
        gB[j] = (const char*)Wc + ((size_t)(nt * 256 + (p >> 7))) * 2048 + (p & 127);
    }
    const int bofs[4] = { 32768 + w * 1024, 32768 + 8192 + w * 1024,
                          32768 + 16384 + w * 1024, 32768 + 24576 + w * 1024 };

    f32x4 acc[8][4] = {};

    // ---- prologue: stage K-tile 0 into buf0 ----
    {
        float4 av[8];
        #pragma unroll
        for (int j = 0; j < 4; ++j) {
            av[2 * j]     = *(const float4*)(gA[j]);
            av[2 * j + 1] = *(const float4*)(gA[j] + 4);
        }
        #pragma unroll
        for (int j = 0; j < 4; ++j)
            gload16(gB[j], lds + bofs[j]);
        #pragma unroll
        for (int j = 0; j < 4; ++j)
            *(u16x8*)(lds + awr[j]) = pack8(av[2 * j], av[2 * j + 1]);
        asm volatile("s_waitcnt vmcnt(0)" ::: "memory");
        asm volatile("s_waitcnt lgkmcnt(0)" ::: "memory");
        __builtin_amdgcn_s_barrier();
    }

#define MFMA16(ACCI, AF, BF)                                                   \
    _Pragma("unroll")                                                          \
    for (int fi = 0; fi < 4; ++fi)                                             \
        _Pragma("unroll")                                                      \
        for (int fj = 0; fj < 4; ++fj)                                         \
            acc[(ACCI) + fi][fj] = __builtin_amdgcn_mfma_f32_16x16x32_bf16(    \
                (AF)[fi], (BF)[fj], acc[(ACCI) + fi][fj], 0, 0, 0)

#define PH_SYNC()                                                              \
    __builtin_amdgcn_s_barrier();                                              \
    asm volatile("s_waitcnt lgkmcnt(0)" ::: "memory");                         \
    __builtin_amdgcn_sched_barrier(0)

#define ITER(T, SEN)                                                           \
    do {                                                                       \
        const int cb = ((T) & 1) << 16;                                        \
        char* cbuf = lds + cb;                                                 \
        char* nbuf = lds + (cb ^ 65536);                                       \
        float4 av[8];                                                          \
        if (SEN) {                                                             \
            _Pragma("unroll")                                                  \
            for (int j = 0; j < 4; ++j) {                                      \
                av[2 * j]     = *(const float4*)(gA[j] + ((T) + 1) * 64);      \
                av[2 * j + 1] = *(const float4*)(gA[j] + ((T) + 1) * 64 + 4);  \
            }                                                                  \
            gload16(gB[0] + ((size_t)(T) + 1) * 128, nbuf + bofs[0]);          \
            gload16(gB[1] + ((size_t)(T) + 1) * 128, nbuf + bofs[1]);          \
        }                                                                      \
        /* P0: B kh0 + A kh0 rows 0-3 */                                       \
        bf16x8 b0[4], a0[4];                                                   \
        _Pragma("unroll")                                                      \
        for (int fj = 0; fj < 4; ++fj)                                         \
            b0[fj] = *(const bf16x8*)(cbuf + boff[fj]);                        \
        _Pragma("unroll")                                                      \
        for (int fi = 0; fi < 4; ++fi)                                         \
            a0[fi] = *(const bf16x8*)(cbuf + aoff[fi]);                        \
        PH_SYNC();                                                             \
        __builtin_amdgcn_s_setprio(1);                                         \
        MFMA16(0, a0, b0);                                                     \
        __builtin_amdgcn_s_setprio(0);                                         \
        __builtin_amdgcn_s_barrier();                                          \
        /* P1: A kh0 rows 4-7; cvt+write A(t+1) j01; issue B j23 */            \
        bf16x8 a1[4];                                                          \
        _Pragma("unroll")                                                      \
        for (int fi = 0; fi < 4; ++fi)                                         \
            a1[fi] = *(const bf16x8*)(cbuf + aoff[4 + fi]);                    \
        if (SEN) {                                                             \
            *(u16x8*)(nbuf + awr[0]) = pack8(av[0], av[1]);                    \
            *(u16x8*)(nbuf + awr[1]) = pack8(av[2], av[3]);                    \
            gload16(gB[2] + ((size_t)(T) + 1) * 128, nbuf + bofs[2]);          \
            gload16(gB[3] + ((size_t)(T) + 1) * 128, nbuf + bofs[3]);          \
        }                                                                      \
        PH_SYNC();                                                             \
        __builtin_amdgcn_s_setprio(1);                                         \
        MFMA16(4, a1, b0);                                                     \
        __builtin_amdgcn_s_setprio(0);                                         \
        __builtin_amdgcn_s_barrier();                                          \
        /* P2: B kh1 + A kh1 rows 0-3; cvt+write A(t+1) j23 */                 \
        bf16x8 b1[4], a2[4];                                                   \
        _Pragma("unroll")                                                      \
        for (int fj = 0; fj < 4; ++fj)                                         \
            b1[fj] = *(const bf16x8*)(cbuf + (boff[fj] ^ 64));                 \
        _Pragma("unroll")                                                      \
        for (int fi = 0; fi < 4; ++fi)                                         \
            a2[fi] = *(const bf16x8*)(cbuf + (aoff[fi] ^ 64));                 \
        if (SEN) {                                                             \
            *(u16x8*)(nbuf + awr[2]) = pack8(av[4], av[5]);                    \
            *(u16x8*)(nbuf + awr[3]) = pack8(av[6], av[7]);                    \
        }                                                                      \
        PH_SYNC();                                                             \
        __builtin_amdgcn_s_setprio(1);                                         \
        MFMA16(0, a2, b1);                                                     \
        __builtin_amdgcn_s_setprio(0);                                         \
        __builtin_amdgcn_s_barrier();                                          \
        /* P3: A kh1 rows 4-7 */                                               \
        bf16x8 a3[4];                                                          \
        _Pragma("unroll")                                                      \
        for (int fi = 0; fi < 4; ++fi)                                         \
            a3[fi] = *(const bf16x8*)(cbuf + (aoff[4 + fi] ^ 64));             \
        PH_SYNC();                                                             \
        __builtin_amdgcn_s_setprio(1);                                         \
        MFMA16(4, a3, b1);                                                     \
        __builtin_amdgcn_s_setprio(0);                                         \
        if (SEN) {                                                             \
            asm volatile("s_waitcnt vmcnt(0)" ::: "memory");                   \
            asm volatile("s_waitcnt lgkmcnt(0)" ::: "memory");                 \
            __builtin_amdgcn_s_barrier();                                      \
        }                                                                      \
    } while (0)

    for (int T = 0; T < NKT - 1; ++T) {
        ITER(T, 1);
    }
    ITER(NKT - 1, 0);
#undef ITER
#undef PH_SYNC
#undef MFMA16

    // epilogue: + bias, leaky_relu, fp32 store
    #pragma unroll
    for (int fi = 0; fi < 8; ++fi)
        #pragma unroll
        for (int fj = 0; fj < 4; ++fj) {
            const int col = nt * 256 + wn * 64 + fj * 16 + lr;
            const float b = bcomb[col];
            #pragma unroll
            for (int r = 0; r < 4; ++r) {
                const int row = mt * 256 + wm * 128 + fi * 16 + lk * 4 + r;
                float v = acc[fi][fj][r] + b;
                out[(size_t)row * NDIM + col] = v >= 0.f ? v : 0.01f * v;
            }
        }
}

// ---------------------------------------------------------------------------
// Fallback main GEMM (fused fp32->bf16 A path, 128x128) if ws is too small.
// ---------------------------------------------------------------------------
__global__ __launch_bounds__(256) void main_gemm_f32(
    const float* __restrict__ X, const unsigned short* __restrict__ Wc,
    const float* __restrict__ bcomb, float* __restrict__ out) {
    __shared__ unsigned short As[128 * 32];
    __shared__ unsigned short Bs[128 * 32];
    const int t = threadIdx.x;
    const int nt = blockIdx.x & 7;
    const int mt = blockIdx.x >> 3;
    const int w = t >> 6, l = t & 63;
    const int wr = (w >> 1) * 64, wcc = (w & 1) * 64;
    const int lr = l & 15, lk = l >> 4;

    f32x4 acc[4][4] = {};

    const int arow = t >> 3;
    const int akq = t & 7;
    const int brow = t >> 2;
    const int bc4 = t & 3;

    for (int kt = 0; kt < KDIM / 32; ++kt) {
        float4 av[4];
        #pragma unroll
        for (int j = 0; j < 4; ++j) {
            const int row = j * 32 + arow;
            av[j] = *(const float4*)&X[(mt * 128 + row) * KDIM + kt * 32 + akq * 4];
        }
        __syncthreads();
        #pragma unroll
        for (int j = 0; j < 4; ++j) {
            const int row = j * 32 + arow;
            u16x4 p = { f2bf(av[j].x), f2bf(av[j].y), f2bf(av[j].z), f2bf(av[j].w) };
            *(u16x4*)&As[row * 32 + akq * 4] = p;
        }
        #pragma unroll
        for (int j = 0; j < 2; ++j) {
            const int row = j * 64 + brow;
            const unsigned short* g = &Wc[(nt * 128 + row) * KDIM + kt * 32 + bc4 * 8];
            unsigned short* ldst = &Bs[(j * 256 + w * 64) * 8];
            gload16(g, ldst);
        }
        __syncthreads();
        bf16x8 af[4], bfr[4];
        #pragma unroll
        for (int fi = 0; fi < 4; ++fi)
            af[fi] = *(bf16x8*)&As[(wr + fi * 16 + lr) * 32 + lk * 8];
        #pragma unroll
        for (int fj = 0; fj < 4; ++fj)
            bfr[fj] = *(bf16x8*)&Bs[(wcc + fj * 16 + lr) * 32 + lk * 8];
        #pragma unroll
        for (int fi = 0; fi < 4; ++fi)
            #pragma unroll
            for (int fj = 0; fj < 4; ++fj)
                acc[fi][fj] = __builtin_amdgcn_mfma_f32_16x16x32_bf16(
                    af[fi], bfr[fj], acc[fi][fj], 0, 0, 0);
    }

    #pragma unroll
    for (int fi = 0; fi < 4; ++fi)
        #pragma unroll
        for (int fj = 0; fj < 4; ++fj) {
            const int col = nt * 128 + wcc + fj * 16 + lr;
            const float b = bcomb[col];
            #pragma unroll
            for (int r = 0; r < 4; ++r) {
                const int row = mt * 128 + wr + fi * 16 + lk * 4 + r;
                float v = acc[fi][fj][r] + b;
                out[row * NDIM + col] = v >= 0.f ? v : 0.01f * v;
            }
        }
}

extern "C" void kernel_launch(void* const* d_in, const int* in_sizes, int n_in,
                              void* d_out, int out_size, void* d_ws, size_t ws_size,
                              hipStream_t stream) {
    const float* xs   = (const float*)d_in[0];
    // d_in[1] mask unused: softmax row-sums are exactly 1.
    const float* Wv   = (const float*)d_in[6];
    const float* bv   = (const float*)d_in[7];
    const float* Wlin = (const float*)d_in[8];
    const float* blin = (const float*)d_in[9];

    unsigned short* Wc = (unsigned short*)d_ws;                         // 2 MB
    float* bcomb = (float*)((char*)d_ws + 2097152);                     // 4 KB
    float* out = (float*)d_out;

    // transient scratch in d_out (64 MB, fully overwritten by the final GEMM)
    unsigned short* Wvt = (unsigned short*)d_out;                       // 2 MB
    unsigned short* Wlb = (unsigned short*)((char*)d_out + 2097152);    // 2 MB

    const size_t NEED = 2101248;
    hipLaunchKernelGGL(prep0_kernel, dim3(768), dim3(256), 0, stream,
                       Wv, Wlin, bv, blin, Wvt, Wlb, bcomb);
    hipLaunchKernelGGL(wcomb_kernel, dim3(256), dim3(256), 0, stream,
                       Wlb, Wvt, Wc);
    if (ws_size >= NEED) {
        (void)hipFuncSetAttribute((const void*)main_fused,
                                  hipFuncAttributeMaxDynamicSharedMemorySize,
                                  131072);
        hipLaunchKernelGGL(main_fused, dim3(256), dim3(512), 131072, stream,
                           xs, Wc, bcomb, out);
    } else {
        hipLaunchKernelGGL(main_gemm_f32, dim3((M_TOT / 128) * (NDIM / 128)),
                           dim3(256), 0, stream, xs, Wc, bcomb, out);
    }
}